// Round 2
// baseline (954.003 us; speedup 1.0000x reference)
//
#include <hip/hip_runtime.h>
#include <hip/hip_bf16.h>
#include <math.h>

#define N_NODES 10000
#define K1 10
#define K2 25
#define DIM 64
#define OUT 128
#define NGRAPH 64

// ---------------------------------------------------------------------------
// Kernel kMean: streaming segmented mean over h2.
// h2 is (N*K1*K2, 64); output h2mean is (N*K1, 64).
// One thread per output float4: row = u>>4, c4 = u&15. 25 loads, fully
// unrolled, immediate offsets (k*256B <= 6144 fits 13-bit signed) -> max MLP.
// No LDS, no barriers. This is the 640 MB HBM stream; must run at BW peak.
// ---------------------------------------------------------------------------
__global__ __launch_bounds__(256) void kMean(const float4* __restrict__ h2,
                                             float4* __restrict__ h2mean)
{
    const int u   = blockIdx.x * 256 + threadIdx.x;  // [0, 100000*16)
    const int row = u >> 4;
    const int c4  = u & 15;
    const float4* p = h2 + (size_t)row * (K2 * DIM / 4) + c4;
    float4 s = make_float4(0.f, 0.f, 0.f, 0.f);
#pragma unroll
    for (int k = 0; k < K2; ++k) {
        float4 v = p[k * (DIM / 4)];
        s.x += v.x; s.y += v.y; s.z += v.z; s.w += v.w;
    }
    const float inv = 1.0f / K2;
    s.x *= inv; s.y *= inv; s.z *= inv; s.w *= inv;
    h2mean[u] = s;
}

// ---------------------------------------------------------------------------
// Kernel kA2: per node (one 256-thread block):
//   for j in 0..9:  x_j = concat(h1[node*10+j], h2mean[node*10+j])  (128)
//                   y_j = relu(x_j @ w0 + b0)                       (128)
//   a12mean[node] = mean_j y_j
// Thread t owns col c=t&127, k-half h=t>>7; w0 half-column in 64 regs.
// x reads from LDS are wave-uniform-address -> broadcast (conflict-free).
// ---------------------------------------------------------------------------
__global__ __launch_bounds__(256, 4) void kA2(const float* __restrict__ h1,
                                              const float* __restrict__ h2mean,
                                              const float* __restrict__ w0,
                                              const float* __restrict__ b0,
                                              float* __restrict__ a12mean)
{
    __shared__ float xbuf[K1][2 * DIM];   // 5 KB
    __shared__ float pbuf[K1][OUT];       // 5 KB

    const int t    = threadIdx.x;
    const int node = blockIdx.x;
    const int c    = t & 127;
    const int h    = t >> 7;

    float w0r[64];
#pragma unroll
    for (int k = 0; k < 64; ++k)
        w0r[k] = w0[(h * 64 + k) * OUT + c];
    const float b0r = b0[c];

    // Stage x: h1 rows -> xbuf[j][0:64], h2mean rows -> xbuf[j][64:128]
    {
        const float4* h1b = (const float4*)(h1 + (size_t)node * (K1 * DIM));
        const float4* mb  = (const float4*)(h2mean + (size_t)node * (K1 * DIM));
        for (int idx = t; idx < K1 * DIM / 4; idx += 256) {   // 160 float4 each
            const int j = idx >> 4, cc = idx & 15;
            ((float4*)&xbuf[j][0])[cc]   = h1b[idx];
            ((float4*)&xbuf[j][DIM])[cc] = mb[idx];
        }
    }
    __syncthreads();

    float myp[K1];
#pragma unroll
    for (int j = 0; j < K1; ++j) {
        const float4* xj = (const float4*)(&xbuf[j][h * DIM]);
        float p = 0.f;
#pragma unroll
        for (int k4 = 0; k4 < 16; ++k4) {
            float4 xv = xj[k4];
            p += xv.x * w0r[4 * k4 + 0] + xv.y * w0r[4 * k4 + 1]
               + xv.z * w0r[4 * k4 + 2] + xv.w * w0r[4 * k4 + 3];
        }
        if (h == 1) pbuf[j][c] = p;
        else        myp[j]     = p;
    }
    __syncthreads();
    if (h == 0) {
        float acc = 0.f;
#pragma unroll
        for (int j = 0; j < K1; ++j) {
            float y = myp[j] + pbuf[j][c] + b0r;
            acc += (y > 0.f ? y : 0.f);
        }
        a12mean[(size_t)node * OUT + c] = acc * (1.0f / K1);
    }
}

// ---------------------------------------------------------------------------
// Kernel kB: 16 nodes / block, 512 threads, 4-way k-split (q = t>>7).
//   a01 = relu(concat(h0, mean_10(h1)) @ w0 + b0)
//   out = relu(concat(a01, a12mean) @ w1 + b1)
//   seg[gid] += out   (sorted gids -> run-length flush, 1 atomic / boundary)
// Register arrays: w0q[32] + w1q[64] (~100 VGPRs, no spill risk).
// ---------------------------------------------------------------------------
__global__ __launch_bounds__(512, 2) void kB(const float* __restrict__ h0,
                                             const float* __restrict__ h1,
                                             const float* __restrict__ w0,
                                             const float* __restrict__ b0,
                                             const float* __restrict__ w1,
                                             const float* __restrict__ b1,
                                             const float* __restrict__ a12mean,
                                             const int*   __restrict__ gids,
                                             float* __restrict__ seg)
{
    __shared__ float x0[16][2 * DIM];    // 8 KB
    __shared__ float x1[16][2 * OUT];    // 16 KB
    __shared__ float pq[4][16][OUT];     // 32 KB

    const int t  = threadIdx.x;
    const int n0 = blockIdx.x * 16;
    const int c  = t & 127;
    const int q  = t >> 7;               // 0..3

    float w0q[32];
#pragma unroll
    for (int k = 0; k < 32; ++k)
        w0q[k] = w0[(q * 32 + k) * OUT + c];

    // h0 rows -> x0[:, 0:64]
    for (int idx = t; idx < 16 * DIM; idx += 512)
        x0[idx >> 6][idx & 63] = h0[(size_t)n0 * DIM + idx];

    // mean over 10 h1 rows -> x0[:, 64:128]
    {
        const int col = t & 63, i0 = t >> 6;   // i0 in 0..7
#pragma unroll
        for (int rep = 0; rep < 2; ++rep) {
            const int i = i0 + rep * 8;
            const float* b = h1 + (size_t)(n0 + i) * (K1 * DIM);
            float s = 0.f;
#pragma unroll
            for (int r = 0; r < K1; ++r) s += b[r * DIM + col];
            x0[i][DIM + col] = s * (1.0f / K1);
        }
    }

    // a12mean rows -> x1[:, 128:256]
    for (int idx = t; idx < 16 * OUT; idx += 512)
        x1[idx >> 7][OUT + (idx & 127)] = a12mean[(size_t)n0 * OUT + idx];
    __syncthreads();

    // a01 matvecs: quarter q covers k in [q*32, q*32+32)
#pragma unroll
    for (int i = 0; i < 16; ++i) {
        const float4* xi = (const float4*)&x0[i][q * 32];
        float p = 0.f;
#pragma unroll
        for (int k4 = 0; k4 < 8; ++k4) {
            float4 v = xi[k4];
            p += v.x * w0q[4 * k4 + 0] + v.y * w0q[4 * k4 + 1]
               + v.z * w0q[4 * k4 + 2] + v.w * w0q[4 * k4 + 3];
        }
        pq[q][i][c] = p;
    }

    // load w1 quarter (k in [q*64, q*64+64)) while pq settles
    float w1q[64];
#pragma unroll
    for (int k = 0; k < 64; ++k)
        w1q[k] = w1[(q * 64 + k) * OUT + c];
    __syncthreads();

    if (q == 0) {
        const float b0r = b0[c];
#pragma unroll
        for (int i = 0; i < 16; ++i) {
            float y = pq[0][i][c] + pq[1][i][c] + pq[2][i][c] + pq[3][i][c] + b0r;
            x1[i][c] = (y > 0.f ? y : 0.f);
        }
    }
    __syncthreads();

    // round-1 matvecs: K=256, quarter q covers k in [q*64, q*64+64)
#pragma unroll
    for (int i = 0; i < 16; ++i) {
        const float4* xi = (const float4*)&x1[i][q * 64];
        float p = 0.f;
#pragma unroll
        for (int k4 = 0; k4 < 16; ++k4) {
            float4 v = xi[k4];
            p += v.x * w1q[4 * k4 + 0] + v.y * w1q[4 * k4 + 1]
               + v.z * w1q[4 * k4 + 2] + v.w * w1q[4 * k4 + 3];
        }
        pq[q][i][c] = p;
    }
    __syncthreads();

    if (q == 0) {
        const float b1r = b1[c];
        int   runGid = gids[n0];
        float runSum = 0.f;
#pragma unroll
        for (int i = 0; i < 16; ++i) {
            float y = pq[0][i][c] + pq[1][i][c] + pq[2][i][c] + pq[3][i][c] + b1r;
            y = (y > 0.f ? y : 0.f);
            const int g = gids[n0 + i];        // wave-uniform
            if (g != runGid) {
                atomicAdd(&seg[runGid * OUT + c], runSum);
                runSum = 0.f; runGid = g;
            }
            runSum += y;
        }
        atomicAdd(&seg[runGid * OUT + c], runSum);
    }
}

// ---------------------------------------------------------------------------
// Kernel kC: readout MLP on seg (64 x 128) -> out (64 x 1). One block/graph.
// ---------------------------------------------------------------------------
__global__ void kC(const float* __restrict__ seg,
                   const float* __restrict__ wr1, const float* __restrict__ br1,
                   const float* __restrict__ wr2, const float* __restrict__ br2,
                   const float* __restrict__ wr3, const float* __restrict__ br3,
                   float* __restrict__ out)
{
    __shared__ float r1[35], r2[35];
    const int g = blockIdx.x, l = threadIdx.x;
    const float* s = seg + (size_t)g * OUT;
    const float SCALE = 1.0507009873554805f;
    const float ALPHA = 1.6732632423543772f;

    if (l < 35) {
        float d = br1[l];
        for (int k = 0; k < OUT; ++k) d += s[k] * wr1[k * 35 + l];
        r1[l] = d > 0.f ? SCALE * d : SCALE * ALPHA * (expf(d) - 1.f);
    }
    __syncthreads();
    if (l < 35) {
        float d = br2[l];
        for (int k = 0; k < 35; ++k) d += r1[k] * wr2[k * 35 + l];
        r2[l] = d > 0.f ? SCALE * d : SCALE * ALPHA * (expf(d) - 1.f);
    }
    __syncthreads();
    if (l == 0) {
        float d = br3[0];
        for (int k = 0; k < 35; ++k) d += r2[k] * wr3[k];
        out[g] = d;
    }
}

extern "C" void kernel_launch(void* const* d_in, const int* in_sizes, int n_in,
                              void* d_out, int out_size, void* d_ws, size_t ws_size,
                              hipStream_t stream)
{
    const float* h0  = (const float*)d_in[0];
    const float* h1  = (const float*)d_in[1];
    const float* h2  = (const float*)d_in[2];
    const float* w0  = (const float*)d_in[3];
    const float* b0  = (const float*)d_in[4];
    const float* w1  = (const float*)d_in[5];
    const float* b1  = (const float*)d_in[6];
    const float* wr1 = (const float*)d_in[7];
    const float* br1 = (const float*)d_in[8];
    const float* wr2 = (const float*)d_in[9];
    const float* br2 = (const float*)d_in[10];
    const float* wr3 = (const float*)d_in[11];
    const float* br3 = (const float*)d_in[12];
    const int*  gids = (const int*)d_in[13];

    float* a12mean = (float*)d_ws;                        // N*128 = 5.12 MB
    float* seg     = a12mean + (size_t)N_NODES * OUT;     // 64*128
    float* h2mean  = seg + (size_t)NGRAPH * OUT;          // N*K1*64 = 25.6 MB
    float* out     = (float*)d_out;

    hipMemsetAsync(seg, 0, NGRAPH * OUT * sizeof(float), stream);
    kMean<<<(N_NODES * K1 * (DIM / 4)) / 256, 256, 0, stream>>>(
        (const float4*)h2, (float4*)h2mean);
    kA2<<<N_NODES, 256, 0, stream>>>(h1, h2mean, w0, b0, a12mean);
    kB<<<N_NODES / 16, 512, 0, stream>>>(h0, h1, w0, b0, w1, b1, a12mean, gids, seg);
    kC<<<NGRAPH, 64, 0, stream>>>(seg, wr1, br1, wr2, br2, wr3, br3, out);
}